// Round 9
// baseline (210.999 us; speedup 1.0000x reference)
//
#include <hip/hip_runtime.h>

#define H 12
#define T 2048
#define HD 64
#define CEMB 768
#define M1 8192   // B*T
#define N1 2304   // 3*C
#define K1 768

typedef __attribute__((ext_vector_type(8))) short bf8;
typedef __attribute__((ext_vector_type(4))) float f4;
typedef __attribute__((ext_vector_type(16))) float f16v;
typedef __attribute__((ext_vector_type(4))) int i4;

__device__ __forceinline__ unsigned short f2bf(float f){
  union { float f; unsigned u; } v; v.f = f;
  unsigned r = v.u + 0x7FFFu + ((v.u >> 16) & 1u);
  return (unsigned short)(r >> 16);
}

__device__ __forceinline__ int cvtpk(float a, float b){
  int r;
  asm("v_cvt_pk_bf16_f32 %0, %1, %2" : "=v"(r) : "v"(a), "v"(b));
  return r;
}

// async global->LDS, 16B per lane; dest = wave-uniform base + lane*16
__device__ __forceinline__ void gload16(const unsigned short* g, unsigned short* l){
  __builtin_amdgcn_global_load_lds((const __attribute__((address_space(1))) void*)g,
                                   (__attribute__((address_space(3))) void*)l, 16, 0, 0);
}

// ---- fused f32->bf16 conversion over x, W_attn, W_o (one launch, 3 ranges) ----
__global__ __launch_bounds__(256) void cvt_all(const float* __restrict__ x,
                                               const float* __restrict__ wa,
                                               const float* __restrict__ wo,
                                               unsigned short* __restrict__ xb,
                                               unsigned short* __restrict__ wab,
                                               unsigned short* __restrict__ wob){
  const int n4x = M1 * K1 / 4, n4a = N1 * K1 / 4, n4o = CEMB * CEMB / 4;
  int i = blockIdx.x * blockDim.x + threadIdx.x;
  const float* in; unsigned short* out; int j;
  if (i < n4x){ in = x; out = xb; j = i; }
  else if (i < n4x + n4a){ in = wa; out = wab; j = i - n4x; }
  else if (i < n4x + n4a + n4o){ in = wo; out = wob; j = i - n4x - n4a; }
  else return;
  float4 v = ((const float4*)in)[j];
  ushort4 o;
  o.x = f2bf(v.x); o.y = f2bf(v.y); o.z = f2bf(v.z); o.w = f2bf(v.w);
  ((ushort4*)out)[j] = o;
}

// ---- QKV projection (m97-style). Q pre-scaled by 0.125*log2(e). V row-major. ----
__global__ __launch_bounds__(256) void gemm_qkv(const unsigned short* __restrict__ A,
                                                const unsigned short* __restrict__ Wb,
                                                const float* __restrict__ bias,
                                                unsigned short* __restrict__ Qb,
                                                unsigned short* __restrict__ Kb,
                                                unsigned short* __restrict__ Vr){
  __shared__ __align__(16) unsigned short As[128][64];
  __shared__ __align__(16) unsigned short Bs[128][64];
  int Lid = blockIdx.x + gridDim.x * blockIdx.y;      // 18*64 = 1152 = 8*144
  int L2 = (Lid & 7) * 144 + (Lid >> 3);
  const int m0 = (L2 / 18) * 128, n0 = (L2 % 18) * 128;
  const int tid = threadIdx.x, w = tid >> 6, lane = tid & 63;
  const int wm = (w >> 1) * 64, wn = (w & 1) * 64;
  const int l15 = lane & 15, g = lane >> 4;
  const int srow = lane >> 3;
  const int scol = ((lane & 7) ^ srow) * 8;
  f4 acc[4][4] = {};
  for (int k0 = 0; k0 < K1; k0 += 64){
    #pragma unroll
    for (int i = 0; i < 4; ++i){
      int rb = i * 32 + w * 8;
      gload16(&A [(size_t)(m0 + rb + srow) * K1 + k0 + scol], &As[rb][0]);
      gload16(&Wb[(size_t)(n0 + rb + srow) * K1 + k0 + scol], &Bs[rb][0]);
    }
    __syncthreads();
    #pragma unroll
    for (int kq = 0; kq < 2; ++kq){
      bf8 a[4], b[4];
      #pragma unroll
      for (int i = 0; i < 4; ++i){
        int row = wm + i * 16 + l15;
        a[i] = *(const bf8*)&As[row][(((kq << 2) + g) ^ (row & 7)) * 8];
      }
      #pragma unroll
      for (int j = 0; j < 4; ++j){
        int row = wn + j * 16 + l15;
        b[j] = *(const bf8*)&Bs[row][(((kq << 2) + g) ^ (row & 7)) * 8];
      }
      #pragma unroll
      for (int i = 0; i < 4; ++i)
        #pragma unroll
        for (int j = 0; j < 4; ++j)
          acc[i][j] = __builtin_amdgcn_mfma_f32_16x16x32_bf16(a[i], b[j], acc[i][j], 0, 0, 0);
    }
    __syncthreads();
  }
  #pragma unroll
  for (int j = 0; j < 4; ++j){
    int ncol = n0 + wn + j * 16 + l15;
    float bv = bias[ncol];
    int which = ncol / CEMB;
    int cc = ncol - which * CEMB;
    int h = cc >> 6, d = cc & 63;
    #pragma unroll
    for (int i = 0; i < 4; ++i){
      #pragma unroll
      for (int r = 0; r < 4; ++r){
        int m = m0 + wm + i * 16 + g * 4 + r;
        int b_ = m >> 11, t = m & 2047;
        size_t idx = ((size_t)(b_ * H + h) * T + t) * HD + d;
        float v = acc[i][j][r] + bv;
        if (which == 0)      Qb[idx] = f2bf(v * 0.18033688f);  // 0.125 * log2(e)
        else if (which == 1) Kb[idx] = f2bf(v);
        else                 Vr[idx] = f2bf(v);
      }
    }
  }
}

// ---- V transpose + kv-quad permute: Vr[bh][t][d] -> Vt[bh][d][perm(t)] ----
__global__ __launch_bounds__(256) void transpose_v(const unsigned short* __restrict__ Vr,
                                                   unsigned short* __restrict__ Vt){
  __shared__ unsigned short Lb[64][66];
  const int bh = blockIdx.y, tt = blockIdx.x;
  const unsigned short* src = Vr + ((size_t)bh * T + tt * 64) * HD;
  unsigned short* dst = Vt + (size_t)bh * HD * T + tt * 64;
  const int tid = threadIdx.x;
  {
    int r = tid >> 2, c = (tid & 3) * 16;
    uint4 v0 = *(const uint4*)&src[r * HD + c];
    uint4 v1 = *(const uint4*)&src[r * HD + c + 8];
    unsigned* lp = (unsigned*)&Lb[r][c];
    lp[0] = v0.x; lp[1] = v0.y; lp[2] = v0.z; lp[3] = v0.w;
    lp[4] = v1.x; lp[5] = v1.y; lp[6] = v1.z; lp[7] = v1.w;
  }
  __syncthreads();
  {
    int d = tid >> 2, tq = tid & 3;
    unsigned ov[8];
    #pragma unroll
    for (int jj = 0; jj < 8; ++jj){
      unsigned lo = Lb[tq * 16 + 2 * jj][d];
      unsigned hi = Lb[tq * 16 + 2 * jj + 1][d];
      ov[jj] = lo | (hi << 16);
    }
    uint4* op = (uint4*)&dst[(size_t)d * T + tq * 16];
    op[0] = make_uint4(ov[0], ov[1], ov[4], ov[5]);   // quads [0,2]
    op[1] = make_uint4(ov[2], ov[3], ov[6], ov[7]);   // quads [1,3]
  }
}

// ---- Flash causal attention v16: TWO q-tiles per wave (balanced pair) ----
// R4/R8 diagnosis: latency-bound, ~6 waves/CU, one serial chain per wave;
// VALU-count cuts were neutral 3x. v16 keeps the PROVEN 1-wave block, staging,
// counted-vmcnt sync, and per-stream numerics byte-identical, but each wave
// owns q-tiles qa=j and qb=63-j sharing one KV sweep 0..qb:
//   loop1 (t<=qa): both streams off the same staged tile -- two independent
//   MFMA/softmax/PV chains interleave in the issue slots (ILP covers the
//   4-deep QK chain + exp2 latency); K/V ds_reads shared by both streams.
//   loop2 (qa<t<=qb): single-stream R8 body for b.
// Pair-sum is constant: every block does exactly 65 tile-computes -> uniform
// block durations, no drain tail. Staging tiles/bh: 1552 vs 2080 (-25%).
// Grid 48x32; longest sweep (j=0) dispatched first. bh pinned per XCD.
__global__ __launch_bounds__(64) void attn(const unsigned short* __restrict__ Qb,
                                           const unsigned short* __restrict__ Kb,
                                           const unsigned short* __restrict__ Vt,
                                           unsigned short* __restrict__ Yb){
  __shared__ __align__(16) unsigned short Ks[2][32][64];
  __shared__ __align__(16) unsigned short Vs[2][64][32];
  const int bh = blockIdx.x;                 // 48 % 8 == 0 -> bh pinned to one XCD
  const int j = (int)blockIdx.y;             // pair index: qa=j, qb=63-j
  const int qa = j, qb = 63 - j;
  const int lane = threadIdx.x;
  const int q31 = lane & 31, hi = lane >> 5;
  const int q0a = qa * 32, q0b = qb * 32;
  const unsigned short* Qp = Qb + (size_t)bh * T * HD;
  const unsigned short* Kp = Kb + (size_t)bh * T * HD;
  const unsigned short* Vp = Vt + (size_t)bh * HD * T;
  const int b_ = bh / H, h = bh % H;

  // staging lane constants (pre-swizzled source chunks; LDS dest is linear)
  const int krow = lane >> 3;                         // 0..7 within 8-row slab
  const int kcs  = ((lane & 7) ^ krow) * 8;           // K: chunk ^ (row&7)
  const int vrow = lane >> 2;                         // 0..15 within 16-row slab
  const int vcs  = ((lane & 3) ^ ((lane >> 4) & 3)) * 8;  // V: chunk ^ ((d>>2)&3)

  // Q fragments for both streams
  bf8 qfa[4], qfb[4];
  #pragma unroll
  for (int ds = 0; ds < 4; ++ds){
    qfa[ds] = *(const bf8*)&Qp[(q0a + q31) * HD + ds * 16 + hi * 8];
    qfb[ds] = *(const bf8*)&Qp[(q0b + q31) * HD + ds * 16 + hi * 8];
  }

  // all-ones bf16 B operand for the row-sum MFMA
  bf8 ones;
  #pragma unroll
  for (int jj = 0; jj < 8; ++jj) ones[jj] = (short)0x3F80;

  f16v o0a = {}, o1a = {}, ola = {};
  f16v o0b = {}, o1b = {}, olb = {};
  float m_a = -1e30f, m_b = -1e30f;

  // prologue: stage tile 0 into buf 0
  #pragma unroll
  for (int it = 0; it < 4; ++it)
    gload16(&Kp[(size_t)(it * 8 + krow) * HD + kcs], &Ks[0][it * 8][0]);
  #pragma unroll
  for (int it = 0; it < 4; ++it)
    gload16(&Vp[(size_t)(it * 16 + vrow) * T + vcs], &Vs[0][it * 16][0]);

  // ================= loop 1: dual-stream tiles t = 0..qa =================
  for (int t = 0; t <= qa; ++t){
    const int cur = t & 1;
    const int kv0 = t * 32;
    {   // stage t+1 (t+1 <= qb always in loop1), counted wait on tile t
      const int nkv = kv0 + 32;
      #pragma unroll
      for (int it = 0; it < 4; ++it)
        gload16(&Kp[(size_t)(nkv + it * 8 + krow) * HD + kcs], &Ks[cur ^ 1][it * 8][0]);
      #pragma unroll
      for (int it = 0; it < 4; ++it)
        gload16(&Vp[(size_t)(it * 16 + vrow) * T + nkv + vcs], &Vs[cur ^ 1][it * 16][0]);
      asm volatile("s_waitcnt vmcnt(8)" ::: "memory");
    }
    __builtin_amdgcn_sched_barrier(0);

    // ---- dual QK^T: shared K fragments feed both streams
    f16v s0a = {}, s0b = {};
    __builtin_amdgcn_s_setprio(1);
    #pragma unroll
    for (int ds = 0; ds < 4; ++ds){
      bf8 kk = *(const bf8*)&Ks[cur][q31][(((2 * ds + hi)) ^ (q31 & 7)) * 8];
      s0a = __builtin_amdgcn_mfma_f32_32x32x16_bf16(kk, qfa[ds], s0a, 0, 0, 0);
      s0b = __builtin_amdgcn_mfma_f32_32x32x16_bf16(kk, qfb[ds], s0b, 0, 0, 0);
    }
    __builtin_amdgcn_s_setprio(0);
    if (t == qa){       // a's diagonal tile: causal mask (b's diagonal is in loop2)
      #pragma unroll
      for (int r = 0; r < 16; ++r){
        int kvr = kv0 + (r & 3) + 8 * (r >> 2) + 4 * hi;
        if (kvr > q0a + q31) s0a[r] = -1e30f;
      }
    }
    // ---- softmax a
    {
      float a0 = fmaxf(fmaxf(s0a[0], s0a[1]), s0a[2]);
      float a1 = fmaxf(fmaxf(s0a[3], s0a[4]), s0a[5]);
      float a2 = fmaxf(fmaxf(s0a[6], s0a[7]), s0a[8]);
      float a3 = fmaxf(fmaxf(s0a[9], s0a[10]), s0a[11]);
      float a4 = fmaxf(fmaxf(s0a[12], s0a[13]), s0a[14]);
      float mx = fmaxf(fmaxf(fmaxf(a0, a1), a2), fmaxf(fmaxf(a3, a4), s0a[15]));
      mx = fmaxf(mx, __shfl_xor(mx, 32));
      if (__any(mx > m_a + 8.f)){
        float mn = fmaxf(m_a, mx);
        float sc_ = __builtin_exp2f(m_a - mn);
        #pragma unroll
        for (int r = 0; r < 16; ++r){
          float s = __shfl(sc_, (r & 3) + 8 * (r >> 2) + 4 * hi);
          o0a[r] *= s; o1a[r] *= s; ola[r] *= s;
        }
        m_a = mn;
      }
      #pragma unroll
      for (int r = 0; r < 16; ++r) s0a[r] = __builtin_exp2f(s0a[r] - m_a);
    }
    // ---- softmax b
    {
      float a0 = fmaxf(fmaxf(s0b[0], s0b[1]), s0b[2]);
      float a1 = fmaxf(fmaxf(s0b[3], s0b[4]), s0b[5]);
      float a2 = fmaxf(fmaxf(s0b[6], s0b[7]), s0b[8]);
      float a3 = fmaxf(fmaxf(s0b[9], s0b[10]), s0b[11]);
      float a4 = fmaxf(fmaxf(s0b[12], s0b[13]), s0b[14]);
      float mx = fmaxf(fmaxf(fmaxf(a0, a1), a2), fmaxf(fmaxf(a3, a4), s0b[15]));
      mx = fmaxf(mx, __shfl_xor(mx, 32));
      if (__any(mx > m_b + 8.f)){
        float mn = fmaxf(m_b, mx);
        float sc_ = __builtin_exp2f(m_b - mn);
        #pragma unroll
        for (int r = 0; r < 16; ++r){
          float s = __shfl(sc_, (r & 3) + 8 * (r >> 2) + 4 * hi);
          o0b[r] *= s; o1b[r] *= s; olb[r] *= s;
        }
        m_b = mn;
      }
      #pragma unroll
      for (int r = 0; r < 16; ++r) s0b[r] = __builtin_exp2f(s0b[r] - m_b);
    }
    // ---- dual PV + row-sums: shared V fragments, 6 independent MFMA chains
    union { i4 i; bf8 h; } paa, pab;
    __builtin_amdgcn_s_setprio(1);
    #pragma unroll
    for (int ks = 0; ks < 2; ++ks){
      const int off = ks * 8;
      paa.i = (i4){ cvtpk(s0a[off], s0a[off+1]), cvtpk(s0a[off+2], s0a[off+3]),
                    cvtpk(s0a[off+4], s0a[off+5]), cvtpk(s0a[off+6], s0a[off+7]) };
      pab.i = (i4){ cvtpk(s0b[off], s0b[off+1]), cvtpk(s0b[off+2], s0b[off+3]),
                    cvtpk(s0b[off+4], s0b[off+5]), cvtpk(s0b[off+6], s0b[off+7]) };
      bf8 v0 = *(const bf8*)&Vs[cur][q31]     [((2 * ks + hi) ^ ((q31 >> 2) & 3)) * 8];
      bf8 v1 = *(const bf8*)&Vs[cur][32 + q31][((2 * ks + hi) ^ ((q31 >> 2) & 3)) * 8];
      o0a = __builtin_amdgcn_mfma_f32_32x32x16_bf16(paa.h, v0, o0a, 0, 0, 0);
      o0b = __builtin_amdgcn_mfma_f32_32x32x16_bf16(pab.h, v0, o0b, 0, 0, 0);
      o1a = __builtin_amdgcn_mfma_f32_32x32x16_bf16(paa.h, v1, o1a, 0, 0, 0);
      o1b = __builtin_amdgcn_mfma_f32_32x32x16_bf16(pab.h, v1, o1b, 0, 0, 0);
      ola = __builtin_amdgcn_mfma_f32_32x32x16_bf16(paa.h, ones, ola, 0, 0, 0);
      olb = __builtin_amdgcn_mfma_f32_32x32x16_bf16(pab.h, ones, olb, 0, 0, 0);
    }
    __builtin_amdgcn_s_setprio(0);
  }

  // ================= loop 2: single-stream tiles t = qa+1..qb =================
  for (int t = qa + 1; t <= qb; ++t){
    const int cur = t & 1;
    const int kv0 = t * 32;
    if (t < qb){
      const int nkv = kv0 + 32;
      #pragma unroll
      for (int it = 0; it < 4; ++it)
        gload16(&Kp[(size_t)(nkv + it * 8 + krow) * HD + kcs], &Ks[cur ^ 1][it * 8][0]);
      #pragma unroll
      for (int it = 0; it < 4; ++it)
        gload16(&Vp[(size_t)(it * 16 + vrow) * T + nkv + vcs], &Vs[cur ^ 1][it * 16][0]);
      asm volatile("s_waitcnt vmcnt(8)" ::: "memory");
    } else {
      asm volatile("s_waitcnt vmcnt(0)" ::: "memory");
    }
    __builtin_amdgcn_sched_barrier(0);

    f16v s0 = {};
    __builtin_amdgcn_s_setprio(1);
    #pragma unroll
    for (int ds = 0; ds < 4; ++ds){
      bf8 kk = *(const bf8*)&Ks[cur][q31][(((2 * ds + hi)) ^ (q31 & 7)) * 8];
      s0 = __builtin_amdgcn_mfma_f32_32x32x16_bf16(kk, qfb[ds], s0, 0, 0, 0);
    }
    __builtin_amdgcn_s_setprio(0);
    if (t == qb){       // b's diagonal tile
      #pragma unroll
      for (int r = 0; r < 16; ++r){
        int kvr = kv0 + (r & 3) + 8 * (r >> 2) + 4 * hi;
        if (kvr > q0b + q31) s0[r] = -1e30f;
      }
    }
    float a0 = fmaxf(fmaxf(s0[0], s0[1]), s0[2]);
    float a1 = fmaxf(fmaxf(s0[3], s0[4]), s0[5]);
    float a2 = fmaxf(fmaxf(s0[6], s0[7]), s0[8]);
    float a3 = fmaxf(fmaxf(s0[9], s0[10]), s0[11]);
    float a4 = fmaxf(fmaxf(s0[12], s0[13]), s0[14]);
    float mx = fmaxf(fmaxf(fmaxf(a0, a1), a2), fmaxf(fmaxf(a3, a4), s0[15]));
    mx = fmaxf(mx, __shfl_xor(mx, 32));
    if (__any(mx > m_b + 8.f)){
      float mn = fmaxf(m_b, mx);
      float sc_ = __builtin_exp2f(m_b - mn);
      #pragma unroll
      for (int r = 0; r < 16; ++r){
        float s = __shfl(sc_, (r & 3) + 8 * (r >> 2) + 4 * hi);
        o0b[r] *= s; o1b[r] *= s; olb[r] *= s;
      }
      m_b = mn;
    }
    #pragma unroll
    for (int r = 0; r < 16; ++r) s0[r] = __builtin_exp2f(s0[r] - m_b);
    union { i4 i; bf8 h; } pa;
    __builtin_amdgcn_s_setprio(1);
    #pragma unroll
    for (int ks = 0; ks < 2; ++ks){
      const int off = ks * 8;
      pa.i = (i4){ cvtpk(s0[off], s0[off+1]), cvtpk(s0[off+2], s0[off+3]),
                   cvtpk(s0[off+4], s0[off+5]), cvtpk(s0[off+6], s0[off+7]) };
      bf8 v0 = *(const bf8*)&Vs[cur][q31]     [((2 * ks + hi) ^ ((q31 >> 2) & 3)) * 8];
      bf8 v1 = *(const bf8*)&Vs[cur][32 + q31][((2 * ks + hi) ^ ((q31 >> 2) & 3)) * 8];
      o0b = __builtin_amdgcn_mfma_f32_32x32x16_bf16(pa.h, v0, o0b, 0, 0, 0);
      o1b = __builtin_amdgcn_mfma_f32_32x32x16_bf16(pa.h, v1, o1b, 0, 0, 0);
      olb = __builtin_amdgcn_mfma_f32_32x32x16_bf16(pa.h, ones, olb, 0, 0, 0);
    }
    __builtin_amdgcn_s_setprio(0);
  }

  // ---- epilogue: per-register exact 1/l, store both streams (bf16)
  #pragma unroll
  for (int r = 0; r < 16; ++r){
    int rr = (r & 3) + 8 * (r >> 2) + 4 * hi;
    float inva = 1.0f / ola[r];
    size_t basea = ((size_t)b_ * T + q0a + rr) * CEMB + h * HD;
    Yb[basea + q31]      = f2bf(o0a[r] * inva);
    Yb[basea + 32 + q31] = f2bf(o1a[r] * inva);
    float invb = 1.0f / olb[r];
    size_t baseb = ((size_t)b_ * T + q0b + rr) * CEMB + h * HD;
    Yb[baseb + q31]      = f2bf(o0b[r] * invb);
    Yb[baseb + 32 + q31] = f2bf(o1b[r] * invb);
  }
}

// ---- Output projection (m97 structure), fp32 out ----
__global__ __launch_bounds__(256) void gemm_out(const unsigned short* __restrict__ A,
                                                const unsigned short* __restrict__ Wb,
                                                const float* __restrict__ bias,
                                                float* __restrict__ out){
  __shared__ __align__(16) unsigned short As[128][64];
  __shared__ __align__(16) unsigned short Bs[128][64];
  int Lid = blockIdx.x + gridDim.x * blockIdx.y;      // 6*64 = 384 = 8*48
  int L2 = (Lid & 7) * 48 + (Lid >> 3);
  const int m0 = (L2 / 6) * 128, n0 = (L2 % 6) * 128;
  const int tid = threadIdx.x, w = tid >> 6, lane = tid & 63;
  const int wm = (w >> 1) * 64, wn = (w & 1) * 64;
  const int l15 = lane & 15, g = lane >> 4;
  const int srow = lane >> 3;
  const int scol = ((lane & 7) ^ srow) * 8;
  f4 acc[4][4] = {};
  for (int k0 = 0; k0 < CEMB; k0 += 64){
    #pragma unroll
    for (int i = 0; i < 4; ++i){
      int rb = i * 32 + w * 8;
      gload16(&A [(size_t)(m0 + rb + srow) * CEMB + k0 + scol], &As[rb][0]);
      gload16(&Wb[(size_t)(n0 + rb + srow) * CEMB + k0 + scol], &Bs[rb][0]);
    }
    __syncthreads();
    #pragma unroll
    for (int kq = 0; kq < 2; ++kq){
      bf8 a[4], b[4];
      #pragma unroll
      for (int i = 0; i < 4; ++i){
        int row = wm + i * 16 + l15;
        a[i] = *(const bf8*)&As[row][(((kq << 2) + g) ^ (row & 7)) * 8];
      }
      #pragma unroll
      for (int j = 0; j < 4; ++j){
        int row = wn + j * 16 + l15;
        b[j] = *(const bf8*)&Bs[row][(((kq << 2) + g) ^ (row & 7)) * 8];
      }
      #pragma unroll
      for (int i = 0; i < 4; ++i)
        #pragma unroll
        for (int j = 0; j < 4; ++j)
          acc[i][j] = __builtin_amdgcn_mfma_f32_16x16x32_bf16(a[i], b[j], acc[i][j], 0, 0, 0);
    }
    __syncthreads();
  }
  #pragma unroll
  for (int j = 0; j < 4; ++j){
    int ncol = n0 + wn + j * 16 + l15;
    float bv = bias[ncol];
    #pragma unroll
    for (int i = 0; i < 4; ++i){
      #pragma unroll
      for (int r = 0; r < 4; ++r){
        int m = m0 + wm + i * 16 + g * 4 + r;
        out[(size_t)m * CEMB + ncol] = acc[i][j][r] + bv;
      }
    }
  }
}

extern "C" void kernel_launch(void* const* d_in, const int* in_sizes, int n_in,
                              void* d_out, int out_size, void* d_ws, size_t ws_size,
                              hipStream_t stream){
  const float* x      = (const float*)d_in[0];
  const float* W_attn = (const float*)d_in[1];
  const float* b_attn = (const float*)d_in[2];
  const float* W_o    = (const float*)d_in[3];
  const float* b_o    = (const float*)d_in[4];
  float* out = (float*)d_out;

  char* ws = (char*)d_ws;
  const size_t SZ_T  = (size_t)48 * T * HD * 2;   // 12.58 MB (== X size)
  const size_t SZ_WA = (size_t)N1 * K1 * 2;
  const size_t SZ_WO = (size_t)CEMB * CEMB * 2;
  unsigned short* Xb = (unsigned short*)(ws);
  unsigned short* Vt = (unsigned short*)(ws);     // aliases Xb (dead after gemm_qkv)
  unsigned short* Wa = (unsigned short*)(ws + SZ_T);
  unsigned short* Wo = (unsigned short*)(ws + SZ_T + SZ_WA);
  unsigned short* Qb = (unsigned short*)(ws + SZ_T + SZ_WA + SZ_WO);
  unsigned short* Kb = (unsigned short*)(ws + SZ_T + SZ_WA + SZ_WO + SZ_T);
  unsigned short* Vr = (unsigned short*)(ws + SZ_T + SZ_WA + SZ_WO + 2 * SZ_T);
  unsigned short* Yb = Vr;                        // Vr dead after transpose_v

  const int n4tot = (M1 * K1 + N1 * K1 + CEMB * CEMB) / 4;
  cvt_all<<<(n4tot + 255) / 256, 256, 0, stream>>>(x, W_attn, W_o, Xb, Wa, Wo);

  gemm_qkv<<<dim3(N1 / 128, M1 / 128), 256, 0, stream>>>(Xb, Wa, b_attn, Qb, Kb, Vr);
  transpose_v<<<dim3(T / 64, 48), 256, 0, stream>>>(Vr, Vt);
  attn<<<dim3(48, 32), 64, 0, stream>>>(Qb, Kb, Vt, Yb);
  gemm_out<<<dim3(CEMB / 128, M1 / 128), 256, 0, stream>>>(Yb, Wo, b_o, out);
}

// Round 10
// 159.331 us; speedup vs baseline: 1.3243x; 1.3243x over previous
//
#include <hip/hip_runtime.h>

#define H 12
#define T 2048
#define HD 64
#define CEMB 768
#define M1 8192   // B*T
#define N1 2304   // 3*C
#define K1 768

typedef __attribute__((ext_vector_type(8))) short bf8;
typedef __attribute__((ext_vector_type(4))) float f4;
typedef __attribute__((ext_vector_type(16))) float f16v;
typedef __attribute__((ext_vector_type(4))) int i4;

__device__ __forceinline__ unsigned short f2bf(float f){
  union { float f; unsigned u; } v; v.f = f;
  unsigned r = v.u + 0x7FFFu + ((v.u >> 16) & 1u);
  return (unsigned short)(r >> 16);
}

__device__ __forceinline__ int cvtpk(float a, float b){
  int r;
  asm("v_cvt_pk_bf16_f32 %0, %1, %2" : "=v"(r) : "v"(a), "v"(b));
  return r;
}

// async global->LDS, 16B per lane; dest = wave-uniform base + lane*16
__device__ __forceinline__ void gload16(const unsigned short* g, unsigned short* l){
  __builtin_amdgcn_global_load_lds((const __attribute__((address_space(1))) void*)g,
                                   (__attribute__((address_space(3))) void*)l, 16, 0, 0);
}

// ---- fused f32->bf16 conversion over x, W_attn, W_o (one launch, 3 ranges) ----
__global__ __launch_bounds__(256) void cvt_all(const float* __restrict__ x,
                                               const float* __restrict__ wa,
                                               const float* __restrict__ wo,
                                               unsigned short* __restrict__ xb,
                                               unsigned short* __restrict__ wab,
                                               unsigned short* __restrict__ wob){
  const int n4x = M1 * K1 / 4, n4a = N1 * K1 / 4, n4o = CEMB * CEMB / 4;
  int i = blockIdx.x * blockDim.x + threadIdx.x;
  const float* in; unsigned short* out; int j;
  if (i < n4x){ in = x; out = xb; j = i; }
  else if (i < n4x + n4a){ in = wa; out = wab; j = i - n4x; }
  else if (i < n4x + n4a + n4o){ in = wo; out = wob; j = i - n4x - n4a; }
  else return;
  float4 v = ((const float4*)in)[j];
  ushort4 o;
  o.x = f2bf(v.x); o.y = f2bf(v.y); o.z = f2bf(v.z); o.w = f2bf(v.w);
  ((ushort4*)out)[j] = o;
}

// ---- QKV projection (m97-style). Q pre-scaled by 0.125*log2(e). ----
// V is written DIRECTLY in the transposed + kv-quad-permuted layout the attn
// kernel consumes (Vt[bh][d][perm(t)]), fusing the old transpose_v kernel:
// within each aligned 16-group of t, dest quad = src quad with 1<->2 swapped.
// Each lane's 4 acc values (r=0..3) span one aligned quad (t = 16a + g*4 + r),
// so the V store is one contiguous ushort4 at column (t&~15) + qd*4.
__global__ __launch_bounds__(256) void gemm_qkv(const unsigned short* __restrict__ A,
                                                const unsigned short* __restrict__ Wb,
                                                const float* __restrict__ bias,
                                                unsigned short* __restrict__ Qb,
                                                unsigned short* __restrict__ Kb,
                                                unsigned short* __restrict__ Vt){
  __shared__ __align__(16) unsigned short As[128][64];
  __shared__ __align__(16) unsigned short Bs[128][64];
  int Lid = blockIdx.x + gridDim.x * blockIdx.y;      // 18*64 = 1152 = 8*144
  int L2 = (Lid & 7) * 144 + (Lid >> 3);
  const int m0 = (L2 / 18) * 128, n0 = (L2 % 18) * 128;
  const int tid = threadIdx.x, w = tid >> 6, lane = tid & 63;
  const int wm = (w >> 1) * 64, wn = (w & 1) * 64;
  const int l15 = lane & 15, g = lane >> 4;
  const int srow = lane >> 3;
  const int scol = ((lane & 7) ^ srow) * 8;
  f4 acc[4][4] = {};
  for (int k0 = 0; k0 < K1; k0 += 64){
    #pragma unroll
    for (int i = 0; i < 4; ++i){
      int rb = i * 32 + w * 8;
      gload16(&A [(size_t)(m0 + rb + srow) * K1 + k0 + scol], &As[rb][0]);
      gload16(&Wb[(size_t)(n0 + rb + srow) * K1 + k0 + scol], &Bs[rb][0]);
    }
    __syncthreads();
    #pragma unroll
    for (int kq = 0; kq < 2; ++kq){
      bf8 a[4], b[4];
      #pragma unroll
      for (int i = 0; i < 4; ++i){
        int row = wm + i * 16 + l15;
        a[i] = *(const bf8*)&As[row][(((kq << 2) + g) ^ (row & 7)) * 8];
      }
      #pragma unroll
      for (int j = 0; j < 4; ++j){
        int row = wn + j * 16 + l15;
        b[j] = *(const bf8*)&Bs[row][(((kq << 2) + g) ^ (row & 7)) * 8];
      }
      #pragma unroll
      for (int i = 0; i < 4; ++i)
        #pragma unroll
        for (int j = 0; j < 4; ++j)
          acc[i][j] = __builtin_amdgcn_mfma_f32_16x16x32_bf16(a[i], b[j], acc[i][j], 0, 0, 0);
    }
    __syncthreads();
  }
  const int qd = ((g & 1) << 1) | (g >> 1);   // kv-quad permute: 1<->2 swap
  #pragma unroll
  for (int j = 0; j < 4; ++j){
    int ncol = n0 + wn + j * 16 + l15;
    float bv = bias[ncol];
    int which = ncol / CEMB;                  // uniform within the 16-col group
    int cc = ncol - which * CEMB;
    int h = cc >> 6, d = cc & 63;
    if (which == 2){
      #pragma unroll
      for (int i = 0; i < 4; ++i){
        int m = m0 + wm + i * 16;             // aligned quad-group base
        int b_ = m >> 11, tb = (m & 2047) + qd * 4;
        ushort4 pk;
        pk.x = f2bf(acc[i][j][0] + bv);
        pk.y = f2bf(acc[i][j][1] + bv);
        pk.z = f2bf(acc[i][j][2] + bv);
        pk.w = f2bf(acc[i][j][3] + bv);
        *(ushort4*)&Vt[((size_t)(b_ * H + h) * HD + d) * T + tb] = pk;
      }
    } else {
      #pragma unroll
      for (int i = 0; i < 4; ++i){
        #pragma unroll
        for (int r = 0; r < 4; ++r){
          int m = m0 + wm + i * 16 + g * 4 + r;
          int b_ = m >> 11, t = m & 2047;
          size_t idx = ((size_t)(b_ * H + h) * T + t) * HD + d;
          float v = acc[i][j][r] + bv;
          if (which == 0) Qb[idx] = f2bf(v * 0.18033688f);  // 0.125 * log2(e)
          else            Kb[idx] = f2bf(v);
        }
      }
    }
  }
}

// ---- Flash causal attention (R8-passing kernel, byte-identical) ----
// R9's 2-stream ILP variant crossed the 128-VGPR occupancy cliff (180 VGPR ->
// 2 waves/SIMD) and regressed 1.56x; reverted. Latency-bound at ~6 waves/CU;
// VALU-count micro-cuts proven neutral 3x; cross-wave LDS sharing broken 3x.
__global__ __launch_bounds__(64) void attn(const unsigned short* __restrict__ Qb,
                                           const unsigned short* __restrict__ Kb,
                                           const unsigned short* __restrict__ Vt,
                                           unsigned short* __restrict__ Yb){
  __shared__ __align__(16) unsigned short Ks[2][32][64];
  __shared__ __align__(16) unsigned short Vs[2][64][32];
  const int bh = blockIdx.x;                 // 48 % 8 == 0 -> bh pinned to one XCD
  const int qidx = 63 - (int)blockIdx.y;     // LPT: heavy q-tiles dispatched first
  const int lane = threadIdx.x;
  const int q31 = lane & 31, hi = lane >> 5;
  const int q0 = qidx * 32;
  const unsigned short* Qp = Qb + (size_t)bh * T * HD;
  const unsigned short* Kp = Kb + (size_t)bh * T * HD;
  const unsigned short* Vp = Vt + (size_t)bh * HD * T;
  const int b_ = bh / H, h = bh % H;

  // staging lane constants (pre-swizzled source chunks; LDS dest is linear)
  const int krow = lane >> 3;                         // 0..7 within 8-row slab
  const int kcs  = ((lane & 7) ^ krow) * 8;           // K: chunk ^ (row&7)
  const int vrow = lane >> 2;                         // 0..15 within 16-row slab
  const int vcs  = ((lane & 3) ^ ((lane >> 4) & 3)) * 8;  // V: chunk ^ ((d>>2)&3)

  // Q fragments (B-operand): lane holds Q[q0+q31][ds*16 + hi*8 .. +8]
  bf8 qf[4];
  #pragma unroll
  for (int ds = 0; ds < 4; ++ds)
    qf[ds] = *(const bf8*)&Qp[(q0 + q31) * HD + ds * 16 + hi * 8];

  // all-ones bf16 B operand for the row-sum MFMA
  bf8 ones;
  #pragma unroll
  for (int j = 0; j < 8; ++j) ones[j] = (short)0x3F80;

  f16v o0 = {}, o1 = {}, ol = {};
  float m_i = -1e30f;
  const int ntw = qidx + 1;

  // prologue: stage tile 0 into buf 0
  #pragma unroll
  for (int it = 0; it < 4; ++it)
    gload16(&Kp[(size_t)(it * 8 + krow) * HD + kcs], &Ks[0][it * 8][0]);
  #pragma unroll
  for (int it = 0; it < 4; ++it)
    gload16(&Vp[(size_t)(it * 16 + vrow) * T + vcs], &Vs[0][it * 16][0]);

  #pragma unroll 2
  for (int t = 0; t < ntw; ++t){
    const int cur = t & 1;
    const int kv0 = t * 32;
    if (t + 1 < ntw){     // stage next tile into other buffer, then counted wait
      const int nkv = kv0 + 32;
      #pragma unroll
      for (int it = 0; it < 4; ++it)
        gload16(&Kp[(size_t)(nkv + it * 8 + krow) * HD + kcs], &Ks[cur ^ 1][it * 8][0]);
      #pragma unroll
      for (int it = 0; it < 4; ++it)
        gload16(&Vp[(size_t)(it * 16 + vrow) * T + nkv + vcs], &Vs[cur ^ 1][it * 16][0]);
      asm volatile("s_waitcnt vmcnt(8)" ::: "memory");
    } else {
      asm volatile("s_waitcnt vmcnt(0)" ::: "memory");
    }
    __builtin_amdgcn_sched_barrier(0);

    // ---- QK^T (swapped): s[kv][q]; K from LDS (XOR-swizzled read)
    f16v s0 = {};
    __builtin_amdgcn_s_setprio(1);
    #pragma unroll
    for (int ds = 0; ds < 4; ++ds){
      bf8 k0 = *(const bf8*)&Ks[cur][q31][(((2 * ds + hi)) ^ (q31 & 7)) * 8];
      s0 = __builtin_amdgcn_mfma_f32_32x32x16_bf16(k0, qf[ds], s0, 0, 0, 0);
    }
    __builtin_amdgcn_s_setprio(0);
    if (t == ntw - 1){    // diagonal tile: causal mask
      #pragma unroll
      for (int r = 0; r < 16; ++r){
        int kvr = kv0 + (r & 3) + 8 * (r >> 2) + 4 * hi;
        if (kvr > q0 + q31) s0[r] = -1e30f;
      }
    }
    // ---- row max: v_max3 triplet tree (identical result, ~7 insts vs ~32)
    float a0 = fmaxf(fmaxf(s0[0], s0[1]), s0[2]);
    float a1 = fmaxf(fmaxf(s0[3], s0[4]), s0[5]);
    float a2 = fmaxf(fmaxf(s0[6], s0[7]), s0[8]);
    float a3 = fmaxf(fmaxf(s0[9], s0[10]), s0[11]);
    float a4 = fmaxf(fmaxf(s0[12], s0[13]), s0[14]);
    float mx = fmaxf(fmaxf(fmaxf(a0, a1), a2), fmaxf(fmaxf(a3, a4), s0[15]));
    mx = fmaxf(mx, __shfl_xor(mx, 32));
    // ---- defer-max: rescale only when max grew by > 8 (log2 domain);
    //      scale redistributed via shfl (row f(r,hi) held by lane q31==row)
    if (__any(mx > m_i + 8.f)){
      float mn = fmaxf(m_i, mx);
      float sc_ = __builtin_exp2f(m_i - mn);
      #pragma unroll
      for (int r = 0; r < 16; ++r){
        float s = __shfl(sc_, (r & 3) + 8 * (r >> 2) + 4 * hi);
        o0[r] *= s; o1[r] *= s; ol[r] *= s;
      }
      m_i = mn;
    }
    // ---- p = exp2(s - m) in place
    #pragma unroll
    for (int r = 0; r < 16; ++r) s0[r] = __builtin_exp2f(s0[r] - m_i);
    // ---- PV + row-sum: A = in-lane pack of own p regs; V^T from LDS;
    //      l accumulated by all-ones MFMA on the matrix pipe
    union { i4 i; bf8 h; } pa;
    __builtin_amdgcn_s_setprio(1);
    #pragma unroll
    for (int ks = 0; ks < 2; ++ks){
      const int off = ks * 8;
      pa.i = (i4){ cvtpk(s0[off], s0[off+1]), cvtpk(s0[off+2], s0[off+3]),
                   cvtpk(s0[off+4], s0[off+5]), cvtpk(s0[off+6], s0[off+7]) };
      bf8 v0 = *(const bf8*)&Vs[cur][q31]     [((2 * ks + hi) ^ ((q31 >> 2) & 3)) * 8];
      bf8 v1 = *(const bf8*)&Vs[cur][32 + q31][((2 * ks + hi) ^ ((q31 >> 2) & 3)) * 8];
      o0 = __builtin_amdgcn_mfma_f32_32x32x16_bf16(pa.h, v0, o0, 0, 0, 0);
      o1 = __builtin_amdgcn_mfma_f32_32x32x16_bf16(pa.h, v1, o1, 0, 0, 0);
      ol = __builtin_amdgcn_mfma_f32_32x32x16_bf16(pa.h, ones, ol, 0, 0, 0);
    }
    __builtin_amdgcn_s_setprio(0);
  }

  // ---- epilogue: per-register exact 1/l, store Y (bf16); no LDS, no cross-lane
  #pragma unroll
  for (int r = 0; r < 16; ++r){
    int qrow = q0 + (r & 3) + 8 * (r >> 2) + 4 * hi;
    float inv = 1.0f / ol[r];
    size_t base = ((size_t)b_ * T + qrow) * CEMB + h * HD;
    Yb[base + q31]      = f2bf(o0[r] * inv);
    Yb[base + 32 + q31] = f2bf(o1[r] * inv);
  }
}

// ---- Output projection (m97 structure), fp32 out ----
__global__ __launch_bounds__(256) void gemm_out(const unsigned short* __restrict__ A,
                                                const unsigned short* __restrict__ Wb,
                                                const float* __restrict__ bias,
                                                float* __restrict__ out){
  __shared__ __align__(16) unsigned short As[128][64];
  __shared__ __align__(16) unsigned short Bs[128][64];
  int Lid = blockIdx.x + gridDim.x * blockIdx.y;      // 6*64 = 384 = 8*48
  int L2 = (Lid & 7) * 48 + (Lid >> 3);
  const int m0 = (L2 / 6) * 128, n0 = (L2 % 6) * 128;
  const int tid = threadIdx.x, w = tid >> 6, lane = tid & 63;
  const int wm = (w >> 1) * 64, wn = (w & 1) * 64;
  const int l15 = lane & 15, g = lane >> 4;
  const int srow = lane >> 3;
  const int scol = ((lane & 7) ^ srow) * 8;
  f4 acc[4][4] = {};
  for (int k0 = 0; k0 < CEMB; k0 += 64){
    #pragma unroll
    for (int i = 0; i < 4; ++i){
      int rb = i * 32 + w * 8;
      gload16(&A [(size_t)(m0 + rb + srow) * CEMB + k0 + scol], &As[rb][0]);
      gload16(&Wb[(size_t)(n0 + rb + srow) * CEMB + k0 + scol], &Bs[rb][0]);
    }
    __syncthreads();
    #pragma unroll
    for (int kq = 0; kq < 2; ++kq){
      bf8 a[4], b[4];
      #pragma unroll
      for (int i = 0; i < 4; ++i){
        int row = wm + i * 16 + l15;
        a[i] = *(const bf8*)&As[row][(((kq << 2) + g) ^ (row & 7)) * 8];
      }
      #pragma unroll
      for (int j = 0; j < 4; ++j){
        int row = wn + j * 16 + l15;
        b[j] = *(const bf8*)&Bs[row][(((kq << 2) + g) ^ (row & 7)) * 8];
      }
      #pragma unroll
      for (int i = 0; i < 4; ++i)
        #pragma unroll
        for (int j = 0; j < 4; ++j)
          acc[i][j] = __builtin_amdgcn_mfma_f32_16x16x32_bf16(a[i], b[j], acc[i][j], 0, 0, 0);
    }
    __syncthreads();
  }
  #pragma unroll
  for (int j = 0; j < 4; ++j){
    int ncol = n0 + wn + j * 16 + l15;
    float bv = bias[ncol];
    #pragma unroll
    for (int i = 0; i < 4; ++i){
      #pragma unroll
      for (int r = 0; r < 4; ++r){
        int m = m0 + wm + i * 16 + g * 4 + r;
        out[(size_t)m * CEMB + ncol] = acc[i][j][r] + bv;
      }
    }
  }
}

extern "C" void kernel_launch(void* const* d_in, const int* in_sizes, int n_in,
                              void* d_out, int out_size, void* d_ws, size_t ws_size,
                              hipStream_t stream){
  const float* x      = (const float*)d_in[0];
  const float* W_attn = (const float*)d_in[1];
  const float* b_attn = (const float*)d_in[2];
  const float* W_o    = (const float*)d_in[3];
  const float* b_o    = (const float*)d_in[4];
  float* out = (float*)d_out;

  char* ws = (char*)d_ws;
  const size_t SZ_T  = (size_t)48 * T * HD * 2;   // 12.58 MB (== X size)
  const size_t SZ_WA = (size_t)N1 * K1 * 2;
  const size_t SZ_WO = (size_t)CEMB * CEMB * 2;
  unsigned short* Xb = (unsigned short*)(ws);
  unsigned short* Wa = (unsigned short*)(ws + SZ_T);
  unsigned short* Wo = (unsigned short*)(ws + SZ_T + SZ_WA);
  unsigned short* Qb = (unsigned short*)(ws + SZ_T + SZ_WA + SZ_WO);
  unsigned short* Kb = (unsigned short*)(ws + SZ_T + SZ_WA + SZ_WO + SZ_T);
  unsigned short* Vt = (unsigned short*)(ws + SZ_T + SZ_WA + SZ_WO + 2 * SZ_T);
  unsigned short* Yb = Xb;   // Xb dead after gemm_qkv; attn writes Y here

  const int n4tot = (M1 * K1 + N1 * K1 + CEMB * CEMB) / 4;
  cvt_all<<<(n4tot + 255) / 256, 256, 0, stream>>>(x, W_attn, W_o, Xb, Wa, Wo);

  gemm_qkv<<<dim3(N1 / 128, M1 / 128), 256, 0, stream>>>(Xb, Wa, b_attn, Qb, Kb, Vt);
  attn<<<dim3(48, 64), 64, 0, stream>>>(Qb, Kb, Vt, Yb);
  gemm_out<<<dim3(CEMB / 128, M1 / 128), 256, 0, stream>>>(Yb, Wo, b_o, out);
}

// Round 11
// 159.330 us; speedup vs baseline: 1.3243x; 1.0000x over previous
//
#include <hip/hip_runtime.h>

#define H 12
#define T 2048
#define HD 64
#define CEMB 768
#define M1 8192   // B*T
#define N1 2304   // 3*C
#define K1 768

typedef __attribute__((ext_vector_type(8))) short bf8;
typedef __attribute__((ext_vector_type(4))) float f4;
typedef __attribute__((ext_vector_type(16))) float f16v;
typedef __attribute__((ext_vector_type(4))) int i4;

__device__ __forceinline__ unsigned short f2bf(float f){
  union { float f; unsigned u; } v; v.f = f;
  unsigned r = v.u + 0x7FFFu + ((v.u >> 16) & 1u);
  return (unsigned short)(r >> 16);
}

__device__ __forceinline__ int cvtpk(float a, float b){
  int r;
  asm("v_cvt_pk_bf16_f32 %0, %1, %2" : "=v"(r) : "v"(a), "v"(b));
  return r;
}

// async global->LDS, 16B per lane; dest = wave-uniform base + lane*16
__device__ __forceinline__ void gload16(const unsigned short* g, unsigned short* l){
  __builtin_amdgcn_global_load_lds((const __attribute__((address_space(1))) void*)g,
                                   (__attribute__((address_space(3))) void*)l, 16, 0, 0);
}

// ---- fused f32->bf16 conversion over x, W_attn, W_o (one launch, 3 ranges) ----
__global__ __launch_bounds__(256) void cvt_all(const float* __restrict__ x,
                                               const float* __restrict__ wa,
                                               const float* __restrict__ wo,
                                               unsigned short* __restrict__ xb,
                                               unsigned short* __restrict__ wab,
                                               unsigned short* __restrict__ wob){
  const int n4x = M1 * K1 / 4, n4a = N1 * K1 / 4, n4o = CEMB * CEMB / 4;
  int i = blockIdx.x * blockDim.x + threadIdx.x;
  const float* in; unsigned short* out; int j;
  if (i < n4x){ in = x; out = xb; j = i; }
  else if (i < n4x + n4a){ in = wa; out = wab; j = i - n4x; }
  else if (i < n4x + n4a + n4o){ in = wo; out = wob; j = i - n4x - n4a; }
  else return;
  float4 v = ((const float4*)in)[j];
  ushort4 o;
  o.x = f2bf(v.x); o.y = f2bf(v.y); o.z = f2bf(v.z); o.w = f2bf(v.w);
  ((ushort4*)out)[j] = o;
}

// ---- QKV projection (m97-style). Q pre-scaled by 0.125*log2(e). ----
// V is written DIRECTLY in the transposed + kv-quad-permuted layout the attn
// kernel consumes (Vt[bh][d][perm(t)]), fusing the old transpose_v kernel:
// within each aligned 16-group of t, dest quad = src quad with 1<->2 swapped.
// Each lane's 4 acc values (r=0..3) span one aligned quad (t = 16a + g*4 + r),
// so the V store is one contiguous ushort4 at column (t&~15) + qd*4.
__global__ __launch_bounds__(256) void gemm_qkv(const unsigned short* __restrict__ A,
                                                const unsigned short* __restrict__ Wb,
                                                const float* __restrict__ bias,
                                                unsigned short* __restrict__ Qb,
                                                unsigned short* __restrict__ Kb,
                                                unsigned short* __restrict__ Vt){
  __shared__ __align__(16) unsigned short As[128][64];
  __shared__ __align__(16) unsigned short Bs[128][64];
  int Lid = blockIdx.x + gridDim.x * blockIdx.y;      // 18*64 = 1152 = 8*144
  int L2 = (Lid & 7) * 144 + (Lid >> 3);
  const int m0 = (L2 / 18) * 128, n0 = (L2 % 18) * 128;
  const int tid = threadIdx.x, w = tid >> 6, lane = tid & 63;
  const int wm = (w >> 1) * 64, wn = (w & 1) * 64;
  const int l15 = lane & 15, g = lane >> 4;
  const int srow = lane >> 3;
  const int scol = ((lane & 7) ^ srow) * 8;
  f4 acc[4][4] = {};
  for (int k0 = 0; k0 < K1; k0 += 64){
    #pragma unroll
    for (int i = 0; i < 4; ++i){
      int rb = i * 32 + w * 8;
      gload16(&A [(size_t)(m0 + rb + srow) * K1 + k0 + scol], &As[rb][0]);
      gload16(&Wb[(size_t)(n0 + rb + srow) * K1 + k0 + scol], &Bs[rb][0]);
    }
    __syncthreads();
    #pragma unroll
    for (int kq = 0; kq < 2; ++kq){
      bf8 a[4], b[4];
      #pragma unroll
      for (int i = 0; i < 4; ++i){
        int row = wm + i * 16 + l15;
        a[i] = *(const bf8*)&As[row][(((kq << 2) + g) ^ (row & 7)) * 8];
      }
      #pragma unroll
      for (int j = 0; j < 4; ++j){
        int row = wn + j * 16 + l15;
        b[j] = *(const bf8*)&Bs[row][(((kq << 2) + g) ^ (row & 7)) * 8];
      }
      #pragma unroll
      for (int i = 0; i < 4; ++i)
        #pragma unroll
        for (int j = 0; j < 4; ++j)
          acc[i][j] = __builtin_amdgcn_mfma_f32_16x16x32_bf16(a[i], b[j], acc[i][j], 0, 0, 0);
    }
    __syncthreads();
  }
  const int qd = ((g & 1) << 1) | (g >> 1);   // kv-quad permute: 1<->2 swap
  #pragma unroll
  for (int j = 0; j < 4; ++j){
    int ncol = n0 + wn + j * 16 + l15;
    float bv = bias[ncol];
    int which = ncol / CEMB;                  // uniform within the 16-col group
    int cc = ncol - which * CEMB;
    int h = cc >> 6, d = cc & 63;
    if (which == 2){
      #pragma unroll
      for (int i = 0; i < 4; ++i){
        int m = m0 + wm + i * 16;             // aligned quad-group base
        int b_ = m >> 11, tb = (m & 2047) + qd * 4;
        ushort4 pk;
        pk.x = f2bf(acc[i][j][0] + bv);
        pk.y = f2bf(acc[i][j][1] + bv);
        pk.z = f2bf(acc[i][j][2] + bv);
        pk.w = f2bf(acc[i][j][3] + bv);
        *(ushort4*)&Vt[((size_t)(b_ * H + h) * HD + d) * T + tb] = pk;
      }
    } else {
      #pragma unroll
      for (int i = 0; i < 4; ++i){
        #pragma unroll
        for (int r = 0; r < 4; ++r){
          int m = m0 + wm + i * 16 + g * 4 + r;
          int b_ = m >> 11, t = m & 2047;
          size_t idx = ((size_t)(b_ * H + h) * T + t) * HD + d;
          float v = acc[i][j][r] + bv;
          if (which == 0) Qb[idx] = f2bf(v * 0.18033688f);  // 0.125 * log2(e)
          else            Kb[idx] = f2bf(v);
        }
      }
    }
  }
}

// ---- Flash causal attention (R8 structure; vmcnt corrected 8 -> 12) ----
// vmcnt FIFO trace of the old vmcnt(8): enter iter t with 8 outstanding (all
// tile-t), issue 12 for t+1 (-> 20), wait <=8 drains 12 oldest = tile-t's 8
// PLUS 4 just-issued loads -- a serialized fresh round-trip (~200+ cyc) every
// tile. Correct count per the staging-depth formula (12 loads x 1 tile in
// flight): vmcnt(12) drains exactly tile-t's remainder and none of t+1's.
__global__ __launch_bounds__(64) void attn(const unsigned short* __restrict__ Qb,
                                           const unsigned short* __restrict__ Kb,
                                           const unsigned short* __restrict__ Vt,
                                           unsigned short* __restrict__ Yb){
  __shared__ __align__(16) unsigned short Ks[2][32][64];
  __shared__ __align__(16) unsigned short Vs[2][64][32];
  const int bh = blockIdx.x;                 // 48 % 8 == 0 -> bh pinned to one XCD
  const int qidx = 63 - (int)blockIdx.y;     // LPT: heavy q-tiles dispatched first
  const int lane = threadIdx.x;
  const int q31 = lane & 31, hi = lane >> 5;
  const int q0 = qidx * 32;
  const unsigned short* Qp = Qb + (size_t)bh * T * HD;
  const unsigned short* Kp = Kb + (size_t)bh * T * HD;
  const unsigned short* Vp = Vt + (size_t)bh * HD * T;
  const int b_ = bh / H, h = bh % H;

  // staging lane constants (pre-swizzled source chunks; LDS dest is linear)
  const int krow = lane >> 3;                         // 0..7 within 8-row slab
  const int kcs  = ((lane & 7) ^ krow) * 8;           // K: chunk ^ (row&7)
  const int vrow = lane >> 2;                         // 0..15 within 16-row slab
  const int vcs  = ((lane & 3) ^ ((lane >> 4) & 3)) * 8;  // V: chunk ^ ((d>>2)&3)

  // Q fragments (B-operand): lane holds Q[q0+q31][ds*16 + hi*8 .. +8]
  bf8 qf[4];
  #pragma unroll
  for (int ds = 0; ds < 4; ++ds)
    qf[ds] = *(const bf8*)&Qp[(q0 + q31) * HD + ds * 16 + hi * 8];

  // all-ones bf16 B operand for the row-sum MFMA
  bf8 ones;
  #pragma unroll
  for (int j = 0; j < 8; ++j) ones[j] = (short)0x3F80;

  f16v o0 = {}, o1 = {}, ol = {};
  float m_i = -1e30f;
  const int ntw = qidx + 1;

  // prologue: stage tile 0 into buf 0
  #pragma unroll
  for (int it = 0; it < 4; ++it)
    gload16(&Kp[(size_t)(it * 8 + krow) * HD + kcs], &Ks[0][it * 8][0]);
  #pragma unroll
  for (int it = 0; it < 4; ++it)
    gload16(&Vp[(size_t)(it * 16 + vrow) * T + vcs], &Vs[0][it * 16][0]);

  #pragma unroll 2
  for (int t = 0; t < ntw; ++t){
    const int cur = t & 1;
    const int kv0 = t * 32;
    if (t + 1 < ntw){     // stage next tile into other buffer, then counted wait
      const int nkv = kv0 + 32;
      #pragma unroll
      for (int it = 0; it < 4; ++it)
        gload16(&Kp[(size_t)(nkv + it * 8 + krow) * HD + kcs], &Ks[cur ^ 1][it * 8][0]);
      #pragma unroll
      for (int it = 0; it < 4; ++it)
        gload16(&Vp[(size_t)(it * 16 + vrow) * T + nkv + vcs], &Vs[cur ^ 1][it * 16][0]);
      asm volatile("s_waitcnt vmcnt(12)" ::: "memory");   // drain tile t only
    } else {
      asm volatile("s_waitcnt vmcnt(0)" ::: "memory");
    }
    __builtin_amdgcn_sched_barrier(0);

    // ---- QK^T (swapped): s[kv][q]; K from LDS (XOR-swizzled read)
    f16v s0 = {};
    __builtin_amdgcn_s_setprio(1);
    #pragma unroll
    for (int ds = 0; ds < 4; ++ds){
      bf8 k0 = *(const bf8*)&Ks[cur][q31][(((2 * ds + hi)) ^ (q31 & 7)) * 8];
      s0 = __builtin_amdgcn_mfma_f32_32x32x16_bf16(k0, qf[ds], s0, 0, 0, 0);
    }
    __builtin_amdgcn_s_setprio(0);
    if (t == ntw - 1){    // diagonal tile: causal mask
      #pragma unroll
      for (int r = 0; r < 16; ++r){
        int kvr = kv0 + (r & 3) + 8 * (r >> 2) + 4 * hi;
        if (kvr > q0 + q31) s0[r] = -1e30f;
      }
    }
    // ---- row max: v_max3 triplet tree (identical result, ~7 insts vs ~32)
    float a0 = fmaxf(fmaxf(s0[0], s0[1]), s0[2]);
    float a1 = fmaxf(fmaxf(s0[3], s0[4]), s0[5]);
    float a2 = fmaxf(fmaxf(s0[6], s0[7]), s0[8]);
    float a3 = fmaxf(fmaxf(s0[9], s0[10]), s0[11]);
    float a4 = fmaxf(fmaxf(s0[12], s0[13]), s0[14]);
    float mx = fmaxf(fmaxf(fmaxf(a0, a1), a2), fmaxf(fmaxf(a3, a4), s0[15]));
    mx = fmaxf(mx, __shfl_xor(mx, 32));
    // ---- defer-max: rescale only when max grew by > 8 (log2 domain);
    //      scale redistributed via shfl (row f(r,hi) held by lane q31==row)
    if (__any(mx > m_i + 8.f)){
      float mn = fmaxf(m_i, mx);
      float sc_ = __builtin_exp2f(m_i - mn);
      #pragma unroll
      for (int r = 0; r < 16; ++r){
        float s = __shfl(sc_, (r & 3) + 8 * (r >> 2) + 4 * hi);
        o0[r] *= s; o1[r] *= s; ol[r] *= s;
      }
      m_i = mn;
    }
    // ---- p = exp2(s - m) in place
    #pragma unroll
    for (int r = 0; r < 16; ++r) s0[r] = __builtin_exp2f(s0[r] - m_i);
    // ---- PV + row-sum: A = in-lane pack of own p regs; V^T from LDS;
    //      l accumulated by all-ones MFMA on the matrix pipe
    union { i4 i; bf8 h; } pa;
    __builtin_amdgcn_s_setprio(1);
    #pragma unroll
    for (int ks = 0; ks < 2; ++ks){
      const int off = ks * 8;
      pa.i = (i4){ cvtpk(s0[off], s0[off+1]), cvtpk(s0[off+2], s0[off+3]),
                   cvtpk(s0[off+4], s0[off+5]), cvtpk(s0[off+6], s0[off+7]) };
      bf8 v0 = *(const bf8*)&Vs[cur][q31]     [((2 * ks + hi) ^ ((q31 >> 2) & 3)) * 8];
      bf8 v1 = *(const bf8*)&Vs[cur][32 + q31][((2 * ks + hi) ^ ((q31 >> 2) & 3)) * 8];
      o0 = __builtin_amdgcn_mfma_f32_32x32x16_bf16(pa.h, v0, o0, 0, 0, 0);
      o1 = __builtin_amdgcn_mfma_f32_32x32x16_bf16(pa.h, v1, o1, 0, 0, 0);
      ol = __builtin_amdgcn_mfma_f32_32x32x16_bf16(pa.h, ones, ol, 0, 0, 0);
    }
    __builtin_amdgcn_s_setprio(0);
  }

  // ---- epilogue: per-register exact 1/l, store Y (bf16); no LDS, no cross-lane
  #pragma unroll
  for (int r = 0; r < 16; ++r){
    int qrow = q0 + (r & 3) + 8 * (r >> 2) + 4 * hi;
    float inv = 1.0f / ol[r];
    size_t base = ((size_t)b_ * T + qrow) * CEMB + h * HD;
    Yb[base + q31]      = f2bf(o0[r] * inv);
    Yb[base + 32 + q31] = f2bf(o1[r] * inv);
  }
}

// ---- Output projection (m97 structure), fp32 out ----
__global__ __launch_bounds__(256) void gemm_out(const unsigned short* __restrict__ A,
                                                const unsigned short* __restrict__ Wb,
                                                const float* __restrict__ bias,
                                                float* __restrict__ out){
  __shared__ __align__(16) unsigned short As[128][64];
  __shared__ __align__(16) unsigned short Bs[128][64];
  int Lid = blockIdx.x + gridDim.x * blockIdx.y;      // 6*64 = 384 = 8*48
  int L2 = (Lid & 7) * 48 + (Lid >> 3);
  const int m0 = (L2 / 6) * 128, n0 = (L2 % 6) * 128;
  const int tid = threadIdx.x, w = tid >> 6, lane = tid & 63;
  const int wm = (w >> 1) * 64, wn = (w & 1) * 64;
  const int l15 = lane & 15, g = lane >> 4;
  const int srow = lane >> 3;
  const int scol = ((lane & 7) ^ srow) * 8;
  f4 acc[4][4] = {};
  for (int k0 = 0; k0 < CEMB; k0 += 64){
    #pragma unroll
    for (int i = 0; i < 4; ++i){
      int rb = i * 32 + w * 8;
      gload16(&A [(size_t)(m0 + rb + srow) * CEMB + k0 + scol], &As[rb][0]);
      gload16(&Wb[(size_t)(n0 + rb + srow) * CEMB + k0 + scol], &Bs[rb][0]);
    }
    __syncthreads();
    #pragma unroll
    for (int kq = 0; kq < 2; ++kq){
      bf8 a[4], b[4];
      #pragma unroll
      for (int i = 0; i < 4; ++i){
        int row = wm + i * 16 + l15;
        a[i] = *(const bf8*)&As[row][(((kq << 2) + g) ^ (row & 7)) * 8];
      }
      #pragma unroll
      for (int j = 0; j < 4; ++j){
        int row = wn + j * 16 + l15;
        b[j] = *(const bf8*)&Bs[row][(((kq << 2) + g) ^ (row & 7)) * 8];
      }
      #pragma unroll
      for (int i = 0; i < 4; ++i)
        #pragma unroll
        for (int j = 0; j < 4; ++j)
          acc[i][j] = __builtin_amdgcn_mfma_f32_16x16x32_bf16(a[i], b[j], acc[i][j], 0, 0, 0);
    }
    __syncthreads();
  }
  #pragma unroll
  for (int j = 0; j < 4; ++j){
    int ncol = n0 + wn + j * 16 + l15;
    float bv = bias[ncol];
    #pragma unroll
    for (int i = 0; i < 4; ++i){
      #pragma unroll
      for (int r = 0; r < 4; ++r){
        int m = m0 + wm + i * 16 + g * 4 + r;
        out[(size_t)m * CEMB + ncol] = acc[i][j][r] + bv;
      }
    }
  }
}

extern "C" void kernel_launch(void* const* d_in, const int* in_sizes, int n_in,
                              void* d_out, int out_size, void* d_ws, size_t ws_size,
                              hipStream_t stream){
  const float* x      = (const float*)d_in[0];
  const float* W_attn = (const float*)d_in[1];
  const float* b_attn = (const float*)d_in[2];
  const float* W_o    = (const float*)d_in[3];
  const float* b_o    = (const float*)d_in[4];
  float* out = (float*)d_out;

  char* ws = (char*)d_ws;
  const size_t SZ_T  = (size_t)48 * T * HD * 2;   // 12.58 MB (== X size)
  const size_t SZ_WA = (size_t)N1 * K1 * 2;
  const size_t SZ_WO = (size_t)CEMB * CEMB * 2;
  unsigned short* Xb = (unsigned short*)(ws);
  unsigned short* Wa = (unsigned short*)(ws + SZ_T);
  unsigned short* Wo = (unsigned short*)(ws + SZ_T + SZ_WA);
  unsigned short* Qb = (unsigned short*)(ws + SZ_T + SZ_WA + SZ_WO);
  unsigned short* Kb = (unsigned short*)(ws + SZ_T + SZ_WA + SZ_WO + SZ_T);
  unsigned short* Vt = (unsigned short*)(ws + SZ_T + SZ_WA + SZ_WO + 2 * SZ_T);
  unsigned short* Yb = Xb;   // Xb dead after gemm_qkv; attn writes Y here

  const int n4tot = (M1 * K1 + N1 * K1 + CEMB * CEMB) / 4;
  cvt_all<<<(n4tot + 255) / 256, 256, 0, stream>>>(x, W_attn, W_o, Xb, Wa, Wo);

  gemm_qkv<<<dim3(N1 / 128, M1 / 128), 256, 0, stream>>>(Xb, Wa, b_attn, Qb, Kb, Vt);
  attn<<<dim3(48, 64), 64, 0, stream>>>(Qb, Kb, Vt, Yb);
  gemm_out<<<dim3(CEMB / 128, M1 / 128), 256, 0, stream>>>(Yb, Wo, b_o, out);
}